// Round 20
// baseline (176.824 us; speedup 1.0000x reference)
//
#include <hip/hip_runtime.h>

typedef short bf16x8 __attribute__((ext_vector_type(8)));
typedef float f32x4 __attribute__((ext_vector_type(4)));
typedef unsigned short u16x8 __attribute__((ext_vector_type(8)));

#define NB 4
#define SQ 2048
#define EM 512
#define NH 8
#define DHD 64
// 1/sqrt(DH) * log2(e): Q pre-scaled so softmax uses exp2
#define QSCALE 0.1803368801111731f

__device__ __forceinline__ unsigned short f2bf(float x) {
  unsigned u = __float_as_uint(x);
  u += 0x7FFFu + ((u >> 16) & 1u);
  return (unsigned short)(u >> 16);
}

__device__ __forceinline__ int sw8(int row, int col8) { return col8 ^ ((row & 7) << 3); }

// async global->LDS, 16B/lane; LDS dest = wave-uniform base + lane*16 (linear).
// Swizzled storage achieved by pre-swizzling the per-lane GLOBAL source address.
__device__ __forceinline__ void glds16(const void* g, void* l) {
  __builtin_amdgcn_global_load_lds(
      (const __attribute__((address_space(1))) void*)g,
      (__attribute__((address_space(3))) void*)l, 16, 0, 0);
}

// ---------------- fused fp32 -> bf16 convert (all 4 weight tensors) ----------------
__global__ __launch_bounds__(256) void f2bf4_kernel(
    const float* __restrict__ w0, const float* __restrict__ w1,
    const float* __restrict__ w2, const float* __restrict__ w3,
    unsigned short* __restrict__ o0, unsigned short* __restrict__ o1,
    unsigned short* __restrict__ o2, unsigned short* __restrict__ o3) {
  int i = (blockIdx.x * 256 + threadIdx.x) * 8;
  const float* src;
  unsigned short* dst;
  int off;
  if (i < 786432) { src = w0; dst = o0; off = i; }
  else if (i < 1048576) { src = w1; dst = o1; off = i - 786432; }
  else if (i < 1310720) { src = w2; dst = o2; off = i - 1048576; }
  else { src = w3; dst = o3; off = i - 1310720; }
  f32x4 a = *(const f32x4*)(src + off);
  f32x4 b = *(const f32x4*)(src + off + 4);
  u16x8 o;
#pragma unroll
  for (int j = 0; j < 4; ++j) { o[j] = f2bf(a[j]); o[j + 4] = f2bf(b[j]); }
  *(u16x8*)(dst + off) = o;
}

// ---------------- LayerNorm (row = E=512), fp32 in -> bf16 out ----------------
__global__ __launch_bounds__(256) void ln_kernel(const float* __restrict__ x,
                                                 const float* __restrict__ g,
                                                 const float* __restrict__ bb,
                                                 unsigned short* __restrict__ out) {
  int tid = threadIdx.x;
  int row = blockIdx.x * 4 + (tid >> 6);
  int lane = tid & 63;
  size_t base = (size_t)row * EM + lane * 8;
  f32x4 v0 = *(const f32x4*)(x + base);
  f32x4 v1 = *(const f32x4*)(x + base + 4);
  float s = 0.f, q = 0.f;
#pragma unroll
  for (int j = 0; j < 4; ++j) { s += v0[j] + v1[j]; q += v0[j] * v0[j] + v1[j] * v1[j]; }
#pragma unroll
  for (int m = 1; m < 64; m <<= 1) { s += __shfl_xor(s, m); q += __shfl_xor(q, m); }
  float mean = s * (1.f / EM);
  float var = q * (1.f / EM) - mean * mean;
  float rs = rsqrtf(var + 1e-5f);
  f32x4 g0 = *(const f32x4*)(g + lane * 8), g1 = *(const f32x4*)(g + lane * 8 + 4);
  f32x4 b0 = *(const f32x4*)(bb + lane * 8), b1 = *(const f32x4*)(bb + lane * 8 + 4);
  u16x8 o;
#pragma unroll
  for (int j = 0; j < 4; ++j) {
    o[j] = f2bf((v0[j] - mean) * rs * g0[j] + b0[j]);
    o[j + 4] = f2bf((v1[j] - mean) * rs * g1[j] + b1[j]);
  }
  *(u16x8*)(out + base) = o;
}

// ---------------- GEMM 64x64: dbuf LDS via global_load_lds (1 barrier/iter) ----------------
template <bool LEAKY, bool RESID, bool OUTF32, bool QKV>
__global__ __launch_bounds__(256) void gemm64(
    const unsigned short* __restrict__ A, const unsigned short* __restrict__ Bm,
    const float* __restrict__ bias, const float* __restrict__ resid,
    float* __restrict__ outf, unsigned short* __restrict__ outh,
    unsigned short* __restrict__ qo, unsigned short* __restrict__ ko,
    unsigned short* __restrict__ vo, int M, int N, int K) {
  __shared__ unsigned short As[2][64][64];
  __shared__ unsigned short Bs[2][64][64];
  int m0 = blockIdx.x * 64, n0 = blockIdx.y * 64;
  int t = threadIdx.x;
  int wv = t >> 6, ln = t & 63, lg = ln >> 4, lr = ln & 15;
  int rsub = ln >> 3;
  int csw = ((ln & 7) ^ rsub) * 8;
  f32x4 acc[4];
#pragma unroll
  for (int c = 0; c < 4; ++c)
#pragma unroll
    for (int r = 0; r < 4; ++r) acc[c][r] = 0.f;

  const unsigned short* ag0 = A + (size_t)(m0 + wv * 16 + rsub) * K + csw;
  const unsigned short* ag1 = A + (size_t)(m0 + wv * 16 + 8 + rsub) * K + csw;
  const unsigned short* bg0 = Bm + (size_t)(n0 + wv * 16 + rsub) * K + csw;
  const unsigned short* bg1 = Bm + (size_t)(n0 + wv * 16 + 8 + rsub) * K + csw;

  glds16(ag0, &As[0][wv * 16][0]);
  glds16(ag1, &As[0][wv * 16 + 8][0]);
  glds16(bg0, &Bs[0][wv * 16][0]);
  glds16(bg1, &Bs[0][wv * 16 + 8][0]);

  int nk = K >> 6;
  for (int ki = 0; ki < nk; ++ki) {
    int cur = ki & 1;
    __syncthreads();
    if (ki + 1 < nk) {
      int nb = cur ^ 1;
      int ko_ = (ki + 1) * 64;
      glds16(ag0 + ko_, &As[nb][wv * 16][0]);
      glds16(ag1 + ko_, &As[nb][wv * 16 + 8][0]);
      glds16(bg0 + ko_, &Bs[nb][wv * 16][0]);
      glds16(bg1 + ko_, &Bs[nb][wv * 16 + 8][0]);
    }
#pragma unroll
    for (int kk = 0; kk < 64; kk += 32) {
      int arw = wv * 16 + lr;
      bf16x8 af = *(const bf16x8*)&As[cur][arw][sw8(arw, kk + lg * 8)];
#pragma unroll
      for (int c = 0; c < 4; ++c) {
        int brw = c * 16 + lr;
        bf16x8 bf = *(const bf16x8*)&Bs[cur][brw][sw8(brw, kk + lg * 8)];
        acc[c] = __builtin_amdgcn_mfma_f32_16x16x32_bf16(af, bf, acc[c], 0, 0, 0);
      }
    }
  }
#pragma unroll
  for (int c = 0; c < 4; ++c) {
    int C_ = n0 + c * 16 + lr;
    float bv = bias[C_];
#pragma unroll
    for (int r = 0; r < 4; ++r) {
      int R_ = m0 + wv * 16 + lg * 4 + r;
      float v = acc[c][r] + bv;
      if (LEAKY) v = v > 0.f ? v : 0.01f * v;
      if (RESID) v += resid[(size_t)R_ * N + C_];
      if (QKV) {
        int which = C_ >> 9, f = C_ & 511, h = f >> 6, d = f & 63;
        int b_ = R_ >> 11, s_ = R_ & 2047;
        if (which == 0) {
          qo[(((size_t)b_ * NH + h) * SQ + s_) * DHD + d] = f2bf(v * QSCALE);
        } else if (which == 1) {
          ko[(((size_t)b_ * NH + h) * SQ + s_) * DHD + d] = f2bf(v);
        } else {
          vo[(((size_t)b_ * NH + h) * DHD + d) * SQ + s_] = f2bf(v);  // V^T [b,h,d,s]
        }
      } else if (OUTF32) {
        outf[(size_t)R_ * N + C_] = v;
      } else {
        outh[(size_t)R_ * N + C_] = f2bf(v);
      }
    }
  }
}

// ---------------- GEMM 128x128 (QKV only): dbuf LDS via glds, 2x2 wave quadrants ----------------
template <bool QKV>
__global__ __launch_bounds__(256) void gemm128(
    const unsigned short* __restrict__ A, const unsigned short* __restrict__ Bm,
    const float* __restrict__ bias, unsigned short* __restrict__ qo,
    unsigned short* __restrict__ ko, unsigned short* __restrict__ vo,
    int M, int N, int K) {
  __shared__ unsigned short As[2][128][64];
  __shared__ unsigned short Bs[2][128][64];
  int m0 = blockIdx.x * 128, n0 = blockIdx.y * 128;
  int t = threadIdx.x;
  int wv = t >> 6, ln = t & 63, lg = ln >> 4, lr = ln & 15;
  int wr = wv >> 1, wc = wv & 1;
  int rsub = ln >> 3;
  int csw = ((ln & 7) ^ rsub) * 8;
  f32x4 acc[4][4];
#pragma unroll
  for (int m = 0; m < 4; ++m)
#pragma unroll
    for (int n = 0; n < 4; ++n)
#pragma unroll
      for (int r = 0; r < 4; ++r) acc[m][n][r] = 0.f;

  const unsigned short* agb = A + (size_t)(m0 + wv * 8 + rsub) * K + csw;
  const unsigned short* bgb = Bm + (size_t)(n0 + wv * 8 + rsub) * K + csw;

#pragma unroll
  for (int i = 0; i < 4; ++i) {
    glds16(agb + (size_t)(i * 32) * K, &As[0][i * 32 + wv * 8][0]);
    glds16(bgb + (size_t)(i * 32) * K, &Bs[0][i * 32 + wv * 8][0]);
  }

  int nk = K >> 6;
  for (int ki = 0; ki < nk; ++ki) {
    int cur = ki & 1;
    __syncthreads();
    if (ki + 1 < nk) {
      int nb = cur ^ 1;
      int ko_ = (ki + 1) * 64;
#pragma unroll
      for (int i = 0; i < 4; ++i) {
        glds16(agb + (size_t)(i * 32) * K + ko_, &As[nb][i * 32 + wv * 8][0]);
        glds16(bgb + (size_t)(i * 32) * K + ko_, &Bs[nb][i * 32 + wv * 8][0]);
      }
    }
#pragma unroll
    for (int kk = 0; kk < 64; kk += 32) {
      bf16x8 af[4], bfr[4];
#pragma unroll
      for (int m = 0; m < 4; ++m) {
        int arw = wr * 64 + m * 16 + lr;
        af[m] = *(const bf16x8*)&As[cur][arw][sw8(arw, kk + lg * 8)];
      }
#pragma unroll
      for (int n = 0; n < 4; ++n) {
        int brw = wc * 64 + n * 16 + lr;
        bfr[n] = *(const bf16x8*)&Bs[cur][brw][sw8(brw, kk + lg * 8)];
      }
#pragma unroll
      for (int m = 0; m < 4; ++m)
#pragma unroll
        for (int n = 0; n < 4; ++n)
          acc[m][n] = __builtin_amdgcn_mfma_f32_16x16x32_bf16(af[m], bfr[n], acc[m][n], 0, 0, 0);
    }
  }

#pragma unroll
  for (int n = 0; n < 4; ++n) {
    int C_ = n0 + wc * 64 + n * 16 + lr;
    float bv = bias[C_];
#pragma unroll
    for (int m = 0; m < 4; ++m) {
#pragma unroll
      for (int r = 0; r < 4; ++r) {
        int R_ = m0 + wr * 64 + m * 16 + lg * 4 + r;
        float v = acc[m][n][r] + bv;
        int which = C_ >> 9, f = C_ & 511, h = f >> 6, d = f & 63;
        int b_ = R_ >> 11, s_ = R_ & 2047;
        if (which == 0) {
          qo[(((size_t)b_ * NH + h) * SQ + s_) * DHD + d] = f2bf(v * QSCALE);
        } else if (which == 1) {
          ko[(((size_t)b_ * NH + h) * SQ + s_) * DHD + d] = f2bf(v);
        } else {
          vo[(((size_t)b_ * NH + h) * DHD + d) * SQ + s_] = f2bf(v);  // V^T [b,h,d,s]
        }
      }
    }
  }
}

// ---------------- Flash attention: KVBLK=64, unpaired q-tiles, XCD-LPT 1D grid ----------------
// lin: xcd = lin&7 (each XCD owns 4 (b,h) groups -> K/V L2-resident);
// idx = lin>>3: qt = 31-(idx>>2) descending (LPT: heavy blocks dispatch first per XCD).
// 40 KB LDS -> 4 blocks/CU residency.
__global__ __launch_bounds__(256) void flash_kernel(
    const unsigned short* __restrict__ Q, const unsigned short* __restrict__ Kb,
    const unsigned short* __restrict__ Vt, unsigned short* __restrict__ ctx,
    float* __restrict__ mstat, float* __restrict__ lstat) {
  __shared__ unsigned short Ks[2][64][64];  // [buf][kpos][dh], swizzled (pre-swz source)
  __shared__ unsigned short Vs[2][64][64];  // [buf][dh][kpos], swizzled
  __shared__ unsigned short Ps[4][16][64];  // per-wave P [q][kpos], swizzled
  int lin = blockIdx.x;
  int xcd = lin & 7, idx = lin >> 3;
  int qt = 31 - (idx >> 2);            // descending work per XCD (LPT)
  int grp = xcd + 8 * (idx & 3);       // (b,h) group, 4 per XCD
  int h = grp & 7, b = grp >> 3;
  int qb = qt * 64;
  int t = threadIdx.x, wv = t >> 6, ln = t & 63, lg = ln >> 4, lr = ln & 15;
  int rsub = ln >> 3;
  int csw = ((ln & 7) ^ rsub) * 8;
  size_t headoff = ((size_t)b * NH + h) * SQ;
  const unsigned short* kg0 = Kb + (headoff + wv * 16 + rsub) * DHD + csw;
  const unsigned short* kg1 = Kb + (headoff + wv * 16 + 8 + rsub) * DHD + csw;
  const unsigned short* vg0 = Vt + (((size_t)b * NH + h) * DHD + wv * 16 + rsub) * SQ + csw;
  const unsigned short* vg1 = Vt + (((size_t)b * NH + h) * DHD + wv * 16 + 8 + rsub) * SQ + csw;

  const unsigned short* qrow = Q + (headoff + qb + wv * 16 + lr) * DHD;
  bf16x8 aq0 = *(const bf16x8*)(qrow + lg * 8);
  bf16x8 aq1 = *(const bf16x8*)(qrow + 32 + lg * 8);

  // ones B-fragment: accumulator col 0 = row-sum of P
  bf16x8 vones;
#pragma unroll
  for (int j = 0; j < 8; ++j) vones[j] = (lr == 0) ? (short)0x3F80 : (short)0;

  f32x4 cacc[4], lacc;
#pragma unroll
  for (int nd = 0; nd < 4; ++nd)
#pragma unroll
    for (int r = 0; r < 4; ++r) cacc[nd][r] = 0.f;
#pragma unroll
  for (int r = 0; r < 4; ++r) lacc[r] = 0.f;
  float mrun[4];
#pragma unroll
  for (int r = 0; r < 4; ++r) mrun[r] = -__builtin_inff();

  int nkt = qt + 1;
  // prologue: issue tile 0 into buf0
  glds16(kg0, &Ks[0][wv * 16][0]);
  glds16(kg1, &Ks[0][wv * 16 + 8][0]);
  glds16(vg0, &Vs[0][wv * 16][0]);
  glds16(vg1, &Vs[0][wv * 16 + 8][0]);

  for (int kt = 0; kt < nkt; ++kt) {
    int cur = kt & 1;
    __syncthreads();  // drains glds -> buf[cur] ready
    if (kt + 1 < nkt) {  // issue next tile into alternate buffer
      int nb = cur ^ 1;
      size_t ko_ = (size_t)(kt + 1) * 64;
      glds16(kg0 + ko_ * DHD, &Ks[nb][wv * 16][0]);
      glds16(kg1 + ko_ * DHD, &Ks[nb][wv * 16 + 8][0]);
      glds16(vg0 + ko_, &Vs[nb][wv * 16][0]);
      glds16(vg1 + ko_, &Vs[nb][wv * 16 + 8][0]);
    }

    // QK^T (Q pre-scaled; scores in log2 units)
    float sv[4][4];
    __builtin_amdgcn_s_setprio(1);
#pragma unroll
    for (int nt = 0; nt < 4; ++nt) {
      f32x4 sf;
#pragma unroll
      for (int r = 0; r < 4; ++r) sf[r] = 0.f;
      int brw = nt * 16 + lr;
      bf16x8 bk0 = *(const bf16x8*)&Ks[cur][brw][sw8(brw, lg * 8)];
      bf16x8 bk1 = *(const bf16x8*)&Ks[cur][brw][sw8(brw, 32 + lg * 8)];
      sf = __builtin_amdgcn_mfma_f32_16x16x32_bf16(aq0, bk0, sf, 0, 0, 0);
      sf = __builtin_amdgcn_mfma_f32_16x16x32_bf16(aq1, bk1, sf, 0, 0, 0);
#pragma unroll
      for (int r = 0; r < 4; ++r) sv[nt][r] = sf[r];
    }
    __builtin_amdgcn_s_setprio(0);
    if (kt == nkt - 1) {  // diagonal tile: causal mask
      int kbase = kt * 64;
#pragma unroll
      for (int nt = 0; nt < 4; ++nt) {
        int kcol = kbase + nt * 16 + lr;
#pragma unroll
        for (int r = 0; r < 4; ++r) {
          int qr = qb + wv * 16 + lg * 4 + r;
          if (kcol > qr) sv[nt][r] = -__builtin_inff();
        }
      }
    }

    // online softmax: lane-local defer-max gate
    float lmax[4];
    bool need = false;
#pragma unroll
    for (int r = 0; r < 4; ++r) {
      lmax[r] = fmaxf(fmaxf(sv[0][r], sv[1][r]), fmaxf(sv[2][r], sv[3][r]));
      need |= (lmax[r] > mrun[r] + 8.f);
    }
    if (__any(need)) {
#pragma unroll
      for (int r = 0; r < 4; ++r) {
        float tm = lmax[r];
#pragma unroll
        for (int m = 1; m < 16; m <<= 1) tm = fmaxf(tm, __shfl_xor(tm, m));
        float mn = fmaxf(mrun[r], tm);
        float sc = exp2f(mrun[r] - mn);  // -inf -> 0 on first tile
        mrun[r] = mn;
        lacc[r] *= sc;
#pragma unroll
        for (int nd = 0; nd < 4; ++nd) cacc[nd][r] *= sc;
      }
    }
    // truncating P-store (bias cancels via ones-column l)
#pragma unroll
    for (int r = 0; r < 4; ++r) {
      int prow = lg * 4 + r;
#pragma unroll
      for (int nt = 0; nt < 4; ++nt) {
        float p = exp2f(sv[nt][r] - mrun[r]);
        Ps[wv][prow][sw8(prow, nt * 16 + lr)] =
            (unsigned short)(__float_as_uint(p) >> 16);
      }
    }

    // PV: A = P, B rows = V^T d-rows (+ ones col for l); per-wave LDS, lgkmcnt orders
    bf16x8 pf0 = *(const bf16x8*)&Ps[wv][lr][sw8(lr, lg * 8)];
    bf16x8 pf1 = *(const bf16x8*)&Ps[wv][lr][sw8(lr, 32 + lg * 8)];
    __builtin_amdgcn_s_setprio(1);
    lacc = __builtin_amdgcn_mfma_f32_16x16x32_bf16(pf0, vones, lacc, 0, 0, 0);
    lacc = __builtin_amdgcn_mfma_f32_16x16x32_bf16(pf1, vones, lacc, 0, 0, 0);
#pragma unroll
    for (int nd = 0; nd < 4; ++nd) {
      int vrw = nd * 16 + lr;
      bf16x8 vf0 = *(const bf16x8*)&Vs[cur][vrw][sw8(vrw, lg * 8)];
      bf16x8 vf1 = *(const bf16x8*)&Vs[cur][vrw][sw8(vrw, 32 + lg * 8)];
      cacc[nd] = __builtin_amdgcn_mfma_f32_16x16x32_bf16(pf0, vf0, cacc[nd], 0, 0, 0);
      cacc[nd] = __builtin_amdgcn_mfma_f32_16x16x32_bf16(pf1, vf1, cacc[nd], 0, 0, 0);
    }
    __builtin_amdgcn_s_setprio(0);
  }

  // epilogue: l lives in lanes lr==0; broadcast within each 16-lane group
  float inv[4];
#pragma unroll
  for (int r = 0; r < 4; ++r) inv[r] = 1.f / __shfl(lacc[r], ln & 48);
#pragma unroll
  for (int nd = 0; nd < 4; ++nd)
#pragma unroll
    for (int r = 0; r < 4; ++r) {
      size_t dst = ((size_t)b * SQ + qb + wv * 16 + lg * 4 + r) * EM + h * DHD + nd * 16 + lr;
      ctx[dst] = f2bf(cacc[nd][r] * inv[r]);
    }
  if (lr == 0) {
#pragma unroll
    for (int r = 0; r < 4; ++r) {
      int row = qb + wv * 16 + lg * 4 + r;
      mstat[headoff + row] = mrun[r];            // log2 units
      lstat[headoff + row] = 0.125f * inv[r];    // 1/(H*l): attnw uses directly
    }
  }
}

// ---------------- attn_weights: 2 k-tiles per block, XCD-swizzled 1D grid ----------------
// lin -> xcd = lin&7; each XCD owns 8 (b,kt2) combos so the shared K panel stays L2-resident.
__global__ __launch_bounds__(256) void attnw_kernel(
    const unsigned short* __restrict__ Q, const unsigned short* __restrict__ Kb,
    const float* __restrict__ mstat, const float* __restrict__ lstat,
    float* __restrict__ aw) {
  int lin = blockIdx.x;
  int xcd = lin & 7, slot = lin >> 3;          // slot 0..255
  int combo = xcd + 8 * (slot >> 5);           // (b,kt2) combo 0..63, 8 per XCD
  int qt = slot & 31;
  int kt2 = combo & 15, b = combo >> 4;
  int qb = qt * 64, kb = kt2 * 128;
  int t = threadIdx.x;
  float* tile = aw + ((size_t)b * SQ + qb) * SQ + kb;
  if (2 * kt2 > qt) {  // both 64-col tiles fully masked -> exact zeros (64x128 region)
    int row = t >> 2, cbase = (t & 3) * 32;
    f32x4 z;
#pragma unroll
    for (int j = 0; j < 4; ++j) z[j] = 0.f;
    float* p = tile + (size_t)row * SQ + cbase;
#pragma unroll
    for (int j = 0; j < 8; ++j) *(f32x4*)(p + j * 4) = z;
    return;
  }
  __shared__ unsigned short Ks[2][2][64][64];  // [dbuf][tile][kpos][dh], 32 KB
  int wv = t >> 6, ln = t & 63, lg = ln >> 4, lr = ln & 15;
  int rsub = ln >> 3;
  int csw = ((ln & 7) ^ rsub) * 8;
  size_t khstride = (size_t)SQ * DHD;
  const unsigned short* kg00 = Kb + (((size_t)b * NH) * SQ + kb + wv * 16 + rsub) * DHD + csw;
  const unsigned short* kg01 = kg00 + (size_t)8 * DHD;
  const unsigned short* kg10 = kg00 + (size_t)64 * DHD;  // second tile rows
  const unsigned short* kg11 = kg00 + (size_t)72 * DHD;
  const unsigned short* qg = Q + (((size_t)b * NH) * SQ + qb + wv * 16 + lr) * DHD + lg * 8;
  size_t mbase = (size_t)b * NH * SQ + qb + wv * 16 + lg * 4;

  // prologue: issue K head0 (both tiles) -> buf0; Q/m/l for head0 (cur) and head1 (next)
  glds16(kg00, &Ks[0][0][wv * 16][0]);
  glds16(kg01, &Ks[0][0][wv * 16 + 8][0]);
  glds16(kg10, &Ks[0][1][wv * 16][0]);
  glds16(kg11, &Ks[0][1][wv * 16 + 8][0]);

  bf16x8 aqc0 = *(const bf16x8*)qg;
  bf16x8 aqc1 = *(const bf16x8*)(qg + 32);
  bf16x8 aqn0 = *(const bf16x8*)(qg + khstride);
  bf16x8 aqn1 = *(const bf16x8*)(qg + khstride + 32);
  float mmc[4], lic[4], mmn[4], lin_[4];
#pragma unroll
  for (int r = 0; r < 4; ++r) {
    mmc[r] = mstat[mbase + r];
    lic[r] = lstat[mbase + r];
    mmn[r] = mstat[mbase + SQ + r];
    lin_[r] = lstat[mbase + SQ + r];
  }

  f32x4 facc[2][4];
#pragma unroll
  for (int j = 0; j < 2; ++j)
#pragma unroll
    for (int nt = 0; nt < 4; ++nt)
#pragma unroll
      for (int r = 0; r < 4; ++r) facc[j][nt][r] = 0.f;

  for (int h = 0; h < NH; ++h) {
    int cur = h & 1;
    __syncthreads();  // drains glds -> Ks[cur] ready
    if (h + 1 < NH) {  // issue next head's K (both tiles) into alternate buffer
      size_t ho = (size_t)(h + 1) * khstride;
      glds16(kg00 + ho, &Ks[cur ^ 1][0][wv * 16][0]);
      glds16(kg01 + ho, &Ks[cur ^ 1][0][wv * 16 + 8][0]);
      glds16(kg10 + ho, &Ks[cur ^ 1][1][wv * 16][0]);
      glds16(kg11 + ho, &Ks[cur ^ 1][1][wv * 16 + 8][0]);
    }

    // compute head h: both tiles with shared Q (no masking here)
#pragma unroll
    for (int nt = 0; nt < 4; ++nt) {
      int brw = nt * 16 + lr;
      f32x4 sf0, sf1;
#pragma unroll
      for (int r = 0; r < 4; ++r) { sf0[r] = 0.f; sf1[r] = 0.f; }
      bf16x8 bk00 = *(const bf16x8*)&Ks[cur][0][brw][sw8(brw, lg * 8)];
      bf16x8 bk01 = *(const bf16x8*)&Ks[cur][0][brw][sw8(brw, 32 + lg * 8)];
      bf16x8 bk10 = *(const bf16x8*)&Ks[cur][1][brw][sw8(brw, lg * 8)];
      bf16x8 bk11 = *(const bf16x8*)&Ks[cur][1][brw][sw8(brw, 32 + lg * 8)];
      sf0 = __builtin_amdgcn_mfma_f32_16x16x32_bf16(aqc0, bk00, sf0, 0, 0, 0);
      sf1 = __builtin_amdgcn_mfma_f32_16x16x32_bf16(aqc0, bk10, sf1, 0, 0, 0);
      sf0 = __builtin_amdgcn_mfma_f32_16x16x32_bf16(aqc1, bk01, sf0, 0, 0, 0);
      sf1 = __builtin_amdgcn_mfma_f32_16x16x32_bf16(aqc1, bk11, sf1, 0, 0, 0);
#pragma unroll
      for (int r = 0; r < 4; ++r) {
        facc[0][nt][r] += exp2f(sf0[r] - mmc[r]) * lic[r];
        facc[1][nt][r] += exp2f(sf1[r] - mmc[r]) * lic[r];
      }
    }

    // rotate Q/m/l pipeline; issue loads for head h+2
    aqc0 = aqn0; aqc1 = aqn1;
#pragma unroll
    for (int r = 0; r < 4; ++r) { mmc[r] = mmn[r]; lic[r] = lin_[r]; }
    if (h + 2 < NH) {
      aqn0 = *(const bf16x8*)(qg + (size_t)(h + 2) * khstride);
      aqn1 = *(const bf16x8*)(qg + (size_t)(h + 2) * khstride + 32);
#pragma unroll
      for (int r = 0; r < 4; ++r) {
        mmn[r] = mstat[mbase + (size_t)(h + 2) * SQ + r];
        lin_[r] = lstat[mbase + (size_t)(h + 2) * SQ + r];
      }
    }
  }

  // write; masking applied once per tile: full-mask / diagonal / none
#pragma unroll
  for (int j = 0; j < 2; ++j) {
    int ktj = 2 * kt2 + j;
    bool fullmask = (ktj > qt);
    bool dg = (ktj == qt);
#pragma unroll
    for (int nt = 0; nt < 4; ++nt) {
      int kc = kb + j * 64 + nt * 16 + lr;
#pragma unroll
      for (int r = 0; r < 4; ++r) {
        int qr = qb + wv * 16 + lg * 4 + r;
        float v = (fullmask || (dg && kc > qr)) ? 0.f : facc[j][nt][r];
        tile[(size_t)(wv * 16 + lg * 4 + r) * SQ + j * 64 + nt * 16 + lr] = v;
      }
    }
  }
}

extern "C" void kernel_launch(void* const* d_in, const int* in_sizes, int n_in,
                              void* d_out, int out_size, void* d_ws, size_t ws_size,
                              hipStream_t stream) {
  (void)in_sizes; (void)n_in; (void)out_size; (void)ws_size;
  const float* x = (const float*)d_in[0];
  const float* ln1g = (const float*)d_in[1];
  const float* ln1b = (const float*)d_in[2];
  const float* wqkv = (const float*)d_in[3];
  const float* bqkv = (const float*)d_in[4];
  const float* wout = (const float*)d_in[5];
  const float* bout = (const float*)d_in[6];
  const float* ln2g = (const float*)d_in[7];
  const float* ln2b = (const float*)d_in[8];
  const float* wfc1 = (const float*)d_in[9];
  const float* bfc1 = (const float*)d_in[10];
  const float* wfc2 = (const float*)d_in[11];
  const float* bfc2 = (const float*)d_in[12];

  char* ws = (char*)d_ws;
  unsigned short* zctx = (unsigned short*)(ws);               // z (bf16), later reused as ctx
  unsigned short* qb_ = (unsigned short*)(ws + 8388608);      // later reused as LN2 out
  unsigned short* kb_ = (unsigned short*)(ws + 16777216);     // later reused as fc1 out
  unsigned short* vb_ = (unsigned short*)(ws + 25165824);     // V^T [b,h,d,s]
  float* z2 = (float*)(ws + 33554432);                        // fp32 residual stream
  float* mstat = (float*)(ws + 50331648);
  float* lstat = (float*)(ws + 50593792);
  unsigned short* wqkv_h = (unsigned short*)(ws + 50855936);
  unsigned short* wout_h = (unsigned short*)(ws + 52428800);
  unsigned short* wfc1_h = (unsigned short*)(ws + 52953088);
  unsigned short* wfc2_h = (unsigned short*)(ws + 53477376);
  unsigned short* y1 = qb_;
  unsigned short* h1 = kb_;

  float* outy = (float*)d_out;
  float* outw = outy + (size_t)NB * SQ * EM;

  f2bf4_kernel<<<768, 256, 0, stream>>>(wqkv, wout, wfc1, wfc2,
                                        wqkv_h, wout_h, wfc1_h, wfc2_h);

  ln_kernel<<<2048, 256, 0, stream>>>(x, ln1g, ln1b, zctx);
  gemm128<true><<<dim3(64, 12), 256, 0, stream>>>(
      zctx, wqkv_h, bqkv, qb_, kb_, vb_, 8192, 1536, 512);
  flash_kernel<<<1024, 256, 0, stream>>>(qb_, kb_, vb_, zctx, mstat, lstat);
  attnw_kernel<<<2048, 256, 0, stream>>>(qb_, kb_, mstat, lstat, outw);
  gemm64<false, true, true, false><<<dim3(128, 8), 256, 0, stream>>>(
      zctx, wout_h, bout, x, z2, nullptr, nullptr, nullptr, nullptr, 8192, 512, 512);
  ln_kernel<<<2048, 256, 0, stream>>>(z2, ln2g, ln2b, y1);
  gemm64<true, false, false, false><<<dim3(128, 8), 256, 0, stream>>>(
      y1, wfc1_h, bfc1, nullptr, nullptr, h1, nullptr, nullptr, nullptr, 8192, 512, 512);
  gemm64<false, true, true, false><<<dim3(128, 8), 256, 0, stream>>>(
      h1, wfc2_h, bfc2, z2, outy, nullptr, nullptr, nullptr, nullptr, 8192, 512, 512);
}

// Round 21
// 170.307 us; speedup vs baseline: 1.0383x; 1.0383x over previous
//
#include <hip/hip_runtime.h>

typedef short bf16x8 __attribute__((ext_vector_type(8)));
typedef float f32x4 __attribute__((ext_vector_type(4)));
typedef unsigned short u16x8 __attribute__((ext_vector_type(8)));

#define NB 4
#define SQ 2048
#define EM 512
#define NH 8
#define DHD 64
// 1/sqrt(DH) * log2(e): Q pre-scaled so softmax uses exp2
#define QSCALE 0.1803368801111731f

__device__ __forceinline__ unsigned short f2bf(float x) {
  unsigned u = __float_as_uint(x);
  u += 0x7FFFu + ((u >> 16) & 1u);
  return (unsigned short)(u >> 16);
}

__device__ __forceinline__ int sw8(int row, int col8) { return col8 ^ ((row & 7) << 3); }

// async global->LDS, 16B/lane; LDS dest = wave-uniform base + lane*16 (linear).
// Swizzled storage achieved by pre-swizzling the per-lane GLOBAL source address.
__device__ __forceinline__ void glds16(const void* g, void* l) {
  __builtin_amdgcn_global_load_lds(
      (const __attribute__((address_space(1))) void*)g,
      (__attribute__((address_space(3))) void*)l, 16, 0, 0);
}

// ---------------- fused fp32 -> bf16 convert (all 4 weight tensors) ----------------
__global__ __launch_bounds__(256) void f2bf4_kernel(
    const float* __restrict__ w0, const float* __restrict__ w1,
    const float* __restrict__ w2, const float* __restrict__ w3,
    unsigned short* __restrict__ o0, unsigned short* __restrict__ o1,
    unsigned short* __restrict__ o2, unsigned short* __restrict__ o3) {
  int i = (blockIdx.x * 256 + threadIdx.x) * 8;
  const float* src;
  unsigned short* dst;
  int off;
  if (i < 786432) { src = w0; dst = o0; off = i; }
  else if (i < 1048576) { src = w1; dst = o1; off = i - 786432; }
  else if (i < 1310720) { src = w2; dst = o2; off = i - 1048576; }
  else { src = w3; dst = o3; off = i - 1310720; }
  f32x4 a = *(const f32x4*)(src + off);
  f32x4 b = *(const f32x4*)(src + off + 4);
  u16x8 o;
#pragma unroll
  for (int j = 0; j < 4; ++j) { o[j] = f2bf(a[j]); o[j + 4] = f2bf(b[j]); }
  *(u16x8*)(dst + off) = o;
}

// ---------------- LayerNorm (row = E=512), fp32 in -> bf16 out ----------------
__global__ __launch_bounds__(256) void ln_kernel(const float* __restrict__ x,
                                                 const float* __restrict__ g,
                                                 const float* __restrict__ bb,
                                                 unsigned short* __restrict__ out) {
  int tid = threadIdx.x;
  int row = blockIdx.x * 4 + (tid >> 6);
  int lane = tid & 63;
  size_t base = (size_t)row * EM + lane * 8;
  f32x4 v0 = *(const f32x4*)(x + base);
  f32x4 v1 = *(const f32x4*)(x + base + 4);
  float s = 0.f, q = 0.f;
#pragma unroll
  for (int j = 0; j < 4; ++j) { s += v0[j] + v1[j]; q += v0[j] * v0[j] + v1[j] * v1[j]; }
#pragma unroll
  for (int m = 1; m < 64; m <<= 1) { s += __shfl_xor(s, m); q += __shfl_xor(q, m); }
  float mean = s * (1.f / EM);
  float var = q * (1.f / EM) - mean * mean;
  float rs = rsqrtf(var + 1e-5f);
  f32x4 g0 = *(const f32x4*)(g + lane * 8), g1 = *(const f32x4*)(g + lane * 8 + 4);
  f32x4 b0 = *(const f32x4*)(bb + lane * 8), b1 = *(const f32x4*)(bb + lane * 8 + 4);
  u16x8 o;
#pragma unroll
  for (int j = 0; j < 4; ++j) {
    o[j] = f2bf((v0[j] - mean) * rs * g0[j] + b0[j]);
    o[j + 4] = f2bf((v1[j] - mean) * rs * g1[j] + b1[j]);
  }
  *(u16x8*)(out + base) = o;
}

// ---------------- GEMM 64x64: dbuf LDS via global_load_lds (1 barrier/iter) ----------------
template <bool LEAKY, bool RESID, bool OUTF32, bool QKV>
__global__ __launch_bounds__(256) void gemm64(
    const unsigned short* __restrict__ A, const unsigned short* __restrict__ Bm,
    const float* __restrict__ bias, const float* __restrict__ resid,
    float* __restrict__ outf, unsigned short* __restrict__ outh,
    unsigned short* __restrict__ qo, unsigned short* __restrict__ ko,
    unsigned short* __restrict__ vo, int M, int N, int K) {
  __shared__ unsigned short As[2][64][64];
  __shared__ unsigned short Bs[2][64][64];
  int m0 = blockIdx.x * 64, n0 = blockIdx.y * 64;
  int t = threadIdx.x;
  int wv = t >> 6, ln = t & 63, lg = ln >> 4, lr = ln & 15;
  int rsub = ln >> 3;
  int csw = ((ln & 7) ^ rsub) * 8;
  f32x4 acc[4];
#pragma unroll
  for (int c = 0; c < 4; ++c)
#pragma unroll
    for (int r = 0; r < 4; ++r) acc[c][r] = 0.f;

  const unsigned short* ag0 = A + (size_t)(m0 + wv * 16 + rsub) * K + csw;
  const unsigned short* ag1 = A + (size_t)(m0 + wv * 16 + 8 + rsub) * K + csw;
  const unsigned short* bg0 = Bm + (size_t)(n0 + wv * 16 + rsub) * K + csw;
  const unsigned short* bg1 = Bm + (size_t)(n0 + wv * 16 + 8 + rsub) * K + csw;

  glds16(ag0, &As[0][wv * 16][0]);
  glds16(ag1, &As[0][wv * 16 + 8][0]);
  glds16(bg0, &Bs[0][wv * 16][0]);
  glds16(bg1, &Bs[0][wv * 16 + 8][0]);

  int nk = K >> 6;
  for (int ki = 0; ki < nk; ++ki) {
    int cur = ki & 1;
    __syncthreads();
    if (ki + 1 < nk) {
      int nb = cur ^ 1;
      int ko_ = (ki + 1) * 64;
      glds16(ag0 + ko_, &As[nb][wv * 16][0]);
      glds16(ag1 + ko_, &As[nb][wv * 16 + 8][0]);
      glds16(bg0 + ko_, &Bs[nb][wv * 16][0]);
      glds16(bg1 + ko_, &Bs[nb][wv * 16 + 8][0]);
    }
#pragma unroll
    for (int kk = 0; kk < 64; kk += 32) {
      int arw = wv * 16 + lr;
      bf16x8 af = *(const bf16x8*)&As[cur][arw][sw8(arw, kk + lg * 8)];
#pragma unroll
      for (int c = 0; c < 4; ++c) {
        int brw = c * 16 + lr;
        bf16x8 bf = *(const bf16x8*)&Bs[cur][brw][sw8(brw, kk + lg * 8)];
        acc[c] = __builtin_amdgcn_mfma_f32_16x16x32_bf16(af, bf, acc[c], 0, 0, 0);
      }
    }
  }
#pragma unroll
  for (int c = 0; c < 4; ++c) {
    int C_ = n0 + c * 16 + lr;
    float bv = bias[C_];
#pragma unroll
    for (int r = 0; r < 4; ++r) {
      int R_ = m0 + wv * 16 + lg * 4 + r;
      float v = acc[c][r] + bv;
      if (LEAKY) v = v > 0.f ? v : 0.01f * v;
      if (RESID) v += resid[(size_t)R_ * N + C_];
      if (QKV) {
        int which = C_ >> 9, f = C_ & 511, h = f >> 6, d = f & 63;
        int b_ = R_ >> 11, s_ = R_ & 2047;
        if (which == 0) {
          qo[(((size_t)b_ * NH + h) * SQ + s_) * DHD + d] = f2bf(v * QSCALE);
        } else if (which == 1) {
          ko[(((size_t)b_ * NH + h) * SQ + s_) * DHD + d] = f2bf(v);
        } else {
          vo[(((size_t)b_ * NH + h) * DHD + d) * SQ + s_] = f2bf(v);  // V^T [b,h,d,s]
        }
      } else if (OUTF32) {
        outf[(size_t)R_ * N + C_] = v;
      } else {
        outh[(size_t)R_ * N + C_] = f2bf(v);
      }
    }
  }
}

// ---------------- GEMM 128x128 QKV: BK=32, 32KB LDS (5 blocks/CU), XCD-local 1D grid ----------------
// lin: xcd = lin&7 owns m0 in [xcd*8, xcd*8+8) x all 12 n0 -> A-rows(1MB)+B(1.5MB) L2-resident.
// BK=32 rows are 64B -> naturally 2-way-bank-free for both glds writes and b128 reads (no swizzle).
__global__ __launch_bounds__(256) void gemm128qkv(
    const unsigned short* __restrict__ A, const unsigned short* __restrict__ Bm,
    const float* __restrict__ bias, unsigned short* __restrict__ qo,
    unsigned short* __restrict__ ko, unsigned short* __restrict__ vo, int K) {
  __shared__ unsigned short As[2][128][32];
  __shared__ unsigned short Bs[2][128][32];
  int lin = blockIdx.x;
  int xcd = lin & 7, idx = lin >> 3;          // idx 0..95
  int m0 = (xcd * 8 + (idx & 7)) * 128;
  int n0 = (idx >> 3) * 128;                  // 0..11
  int t = threadIdx.x;
  int wv = t >> 6, ln = t & 63, lg = ln >> 4, lr = ln & 15;
  int wr = wv >> 1, wc = wv & 1;
  int row16 = ln >> 2, chunk = (ln & 3) * 8;  // 16 rows/glds, 4 lanes/row
  f32x4 acc[4][4];
#pragma unroll
  for (int m = 0; m < 4; ++m)
#pragma unroll
    for (int n = 0; n < 4; ++n)
#pragma unroll
      for (int r = 0; r < 4; ++r) acc[m][n][r] = 0.f;

  const unsigned short* agA = A + (size_t)(m0 + wv * 16 + row16) * K + chunk;
  const unsigned short* agB = A + (size_t)(m0 + 64 + wv * 16 + row16) * K + chunk;
  const unsigned short* bgA = Bm + (size_t)(n0 + wv * 16 + row16) * K + chunk;
  const unsigned short* bgB = Bm + (size_t)(n0 + 64 + wv * 16 + row16) * K + chunk;

  // prologue: issue tile 0 into buf 0 (4 glds/wave)
  glds16(agA, &As[0][wv * 16][0]);
  glds16(agB, &As[0][64 + wv * 16][0]);
  glds16(bgA, &Bs[0][wv * 16][0]);
  glds16(bgB, &Bs[0][64 + wv * 16][0]);

  int nk = K >> 5;  // 16
  for (int ki = 0; ki < nk; ++ki) {
    int cur = ki & 1;
    __syncthreads();  // drains glds -> buf[cur] ready
    if (ki + 1 < nk) {
      int nb = cur ^ 1;
      int ko_ = (ki + 1) * 32;
      glds16(agA + ko_, &As[nb][wv * 16][0]);
      glds16(agB + ko_, &As[nb][64 + wv * 16][0]);
      glds16(bgA + ko_, &Bs[nb][wv * 16][0]);
      glds16(bgB + ko_, &Bs[nb][64 + wv * 16][0]);
    }
    bf16x8 af[4], bfr[4];
#pragma unroll
    for (int m = 0; m < 4; ++m)
      af[m] = *(const bf16x8*)&As[cur][wr * 64 + m * 16 + lr][lg * 8];
#pragma unroll
    for (int n = 0; n < 4; ++n)
      bfr[n] = *(const bf16x8*)&Bs[cur][wc * 64 + n * 16 + lr][lg * 8];
#pragma unroll
    for (int m = 0; m < 4; ++m)
#pragma unroll
      for (int n = 0; n < 4; ++n)
        acc[m][n] = __builtin_amdgcn_mfma_f32_16x16x32_bf16(af[m], bfr[n], acc[m][n], 0, 0, 0);
  }

#pragma unroll
  for (int n = 0; n < 4; ++n) {
    int C_ = n0 + wc * 64 + n * 16 + lr;
    float bv = bias[C_];
#pragma unroll
    for (int m = 0; m < 4; ++m) {
#pragma unroll
      for (int r = 0; r < 4; ++r) {
        int R_ = m0 + wr * 64 + m * 16 + lg * 4 + r;
        float v = acc[m][n][r] + bv;
        int which = C_ >> 9, f = C_ & 511, h = f >> 6, d = f & 63;
        int b_ = R_ >> 11, s_ = R_ & 2047;
        if (which == 0) {
          qo[(((size_t)b_ * NH + h) * SQ + s_) * DHD + d] = f2bf(v * QSCALE);
        } else if (which == 1) {
          ko[(((size_t)b_ * NH + h) * SQ + s_) * DHD + d] = f2bf(v);
        } else {
          vo[(((size_t)b_ * NH + h) * DHD + d) * SQ + s_] = f2bf(v);  // V^T [b,h,d,s]
        }
      }
    }
  }
}

// ---------------- Flash attention: KVBLK=64, unpaired q-tiles, XCD-LPT 1D grid ----------------
__global__ __launch_bounds__(256) void flash_kernel(
    const unsigned short* __restrict__ Q, const unsigned short* __restrict__ Kb,
    const unsigned short* __restrict__ Vt, unsigned short* __restrict__ ctx,
    float* __restrict__ mstat, float* __restrict__ lstat) {
  __shared__ unsigned short Ks[2][64][64];  // [buf][kpos][dh], swizzled (pre-swz source)
  __shared__ unsigned short Vs[2][64][64];  // [buf][dh][kpos], swizzled
  __shared__ unsigned short Ps[4][16][64];  // per-wave P [q][kpos], swizzled
  int lin = blockIdx.x;
  int xcd = lin & 7, idx = lin >> 3;
  int qt = 31 - (idx >> 2);            // descending work per XCD (LPT)
  int grp = xcd + 8 * (idx & 3);       // (b,h) group, 4 per XCD
  int h = grp & 7, b = grp >> 3;
  int qb = qt * 64;
  int t = threadIdx.x, wv = t >> 6, ln = t & 63, lg = ln >> 4, lr = ln & 15;
  int rsub = ln >> 3;
  int csw = ((ln & 7) ^ rsub) * 8;
  size_t headoff = ((size_t)b * NH + h) * SQ;
  const unsigned short* kg0 = Kb + (headoff + wv * 16 + rsub) * DHD + csw;
  const unsigned short* kg1 = Kb + (headoff + wv * 16 + 8 + rsub) * DHD + csw;
  const unsigned short* vg0 = Vt + (((size_t)b * NH + h) * DHD + wv * 16 + rsub) * SQ + csw;
  const unsigned short* vg1 = Vt + (((size_t)b * NH + h) * DHD + wv * 16 + 8 + rsub) * SQ + csw;

  const unsigned short* qrow = Q + (headoff + qb + wv * 16 + lr) * DHD;
  bf16x8 aq0 = *(const bf16x8*)(qrow + lg * 8);
  bf16x8 aq1 = *(const bf16x8*)(qrow + 32 + lg * 8);

  // ones B-fragment: accumulator col 0 = row-sum of P
  bf16x8 vones;
#pragma unroll
  for (int j = 0; j < 8; ++j) vones[j] = (lr == 0) ? (short)0x3F80 : (short)0;

  f32x4 cacc[4], lacc;
#pragma unroll
  for (int nd = 0; nd < 4; ++nd)
#pragma unroll
    for (int r = 0; r < 4; ++r) cacc[nd][r] = 0.f;
#pragma unroll
  for (int r = 0; r < 4; ++r) lacc[r] = 0.f;
  float mrun[4];
#pragma unroll
  for (int r = 0; r < 4; ++r) mrun[r] = -__builtin_inff();

  int nkt = qt + 1;
  // prologue: issue tile 0 into buf0
  glds16(kg0, &Ks[0][wv * 16][0]);
  glds16(kg1, &Ks[0][wv * 16 + 8][0]);
  glds16(vg0, &Vs[0][wv * 16][0]);
  glds16(vg1, &Vs[0][wv * 16 + 8][0]);

  for (int kt = 0; kt < nkt; ++kt) {
    int cur = kt & 1;
    __syncthreads();  // drains glds -> buf[cur] ready
    if (kt + 1 < nkt) {  // issue next tile into alternate buffer
      int nb = cur ^ 1;
      size_t ko_ = (size_t)(kt + 1) * 64;
      glds16(kg0 + ko_ * DHD, &Ks[nb][wv * 16][0]);
      glds16(kg1 + ko_ * DHD, &Ks[nb][wv * 16 + 8][0]);
      glds16(vg0 + ko_, &Vs[nb][wv * 16][0]);
      glds16(vg1 + ko_, &Vs[nb][wv * 16 + 8][0]);
    }

    // QK^T (Q pre-scaled; scores in log2 units)
    float sv[4][4];
    __builtin_amdgcn_s_setprio(1);
#pragma unroll
    for (int nt = 0; nt < 4; ++nt) {
      f32x4 sf;
#pragma unroll
      for (int r = 0; r < 4; ++r) sf[r] = 0.f;
      int brw = nt * 16 + lr;
      bf16x8 bk0 = *(const bf16x8*)&Ks[cur][brw][sw8(brw, lg * 8)];
      bf16x8 bk1 = *(const bf16x8*)&Ks[cur][brw][sw8(brw, 32 + lg * 8)];
      sf = __builtin_amdgcn_mfma_f32_16x16x32_bf16(aq0, bk0, sf, 0, 0, 0);
      sf = __builtin_amdgcn_mfma_f32_16x16x32_bf16(aq1, bk1, sf, 0, 0, 0);
#pragma unroll
      for (int r = 0; r < 4; ++r) sv[nt][r] = sf[r];
    }
    __builtin_amdgcn_s_setprio(0);
    if (kt == nkt - 1) {  // diagonal tile: causal mask
      int kbase = kt * 64;
#pragma unroll
      for (int nt = 0; nt < 4; ++nt) {
        int kcol = kbase + nt * 16 + lr;
#pragma unroll
        for (int r = 0; r < 4; ++r) {
          int qr = qb + wv * 16 + lg * 4 + r;
          if (kcol > qr) sv[nt][r] = -__builtin_inff();
        }
      }
    }

    // online softmax: lane-local defer-max gate
    float lmax[4];
    bool need = false;
#pragma unroll
    for (int r = 0; r < 4; ++r) {
      lmax[r] = fmaxf(fmaxf(sv[0][r], sv[1][r]), fmaxf(sv[2][r], sv[3][r]));
      need |= (lmax[r] > mrun[r] + 8.f);
    }
    if (__any(need)) {
#pragma unroll
      for (int r = 0; r < 4; ++r) {
        float tm = lmax[r];
#pragma unroll
        for (int m = 1; m < 16; m <<= 1) tm = fmaxf(tm, __shfl_xor(tm, m));
        float mn = fmaxf(mrun[r], tm);
        float sc = exp2f(mrun[r] - mn);  // -inf -> 0 on first tile
        mrun[r] = mn;
        lacc[r] *= sc;
#pragma unroll
        for (int nd = 0; nd < 4; ++nd) cacc[nd][r] *= sc;
      }
    }
    // truncating P-store (bias cancels via ones-column l)
#pragma unroll
    for (int r = 0; r < 4; ++r) {
      int prow = lg * 4 + r;
#pragma unroll
      for (int nt = 0; nt < 4; ++nt) {
        float p = exp2f(sv[nt][r] - mrun[r]);
        Ps[wv][prow][sw8(prow, nt * 16 + lr)] =
            (unsigned short)(__float_as_uint(p) >> 16);
      }
    }

    // PV: A = P, B rows = V^T d-rows (+ ones col for l); per-wave LDS, lgkmcnt orders
    bf16x8 pf0 = *(const bf16x8*)&Ps[wv][lr][sw8(lr, lg * 8)];
    bf16x8 pf1 = *(const bf16x8*)&Ps[wv][lr][sw8(lr, 32 + lg * 8)];
    __builtin_amdgcn_s_setprio(1);
    lacc = __builtin_amdgcn_mfma_f32_16x16x32_bf16(pf0, vones, lacc, 0, 0, 0);
    lacc = __builtin_amdgcn_mfma_f32_16x16x32_bf16(pf1, vones, lacc, 0, 0, 0);
#pragma unroll
    for (int nd = 0; nd < 4; ++nd) {
      int vrw = nd * 16 + lr;
      bf16x8 vf0 = *(const bf16x8*)&Vs[cur][vrw][sw8(vrw, lg * 8)];
      bf16x8 vf1 = *(const bf16x8*)&Vs[cur][vrw][sw8(vrw, 32 + lg * 8)];
      cacc[nd] = __builtin_amdgcn_mfma_f32_16x16x32_bf16(pf0, vf0, cacc[nd], 0, 0, 0);
      cacc[nd] = __builtin_amdgcn_mfma_f32_16x16x32_bf16(pf1, vf1, cacc[nd], 0, 0, 0);
    }
    __builtin_amdgcn_s_setprio(0);
  }

  // epilogue: l lives in lanes lr==0; broadcast within each 16-lane group
  float inv[4];
#pragma unroll
  for (int r = 0; r < 4; ++r) inv[r] = 1.f / __shfl(lacc[r], ln & 48);
#pragma unroll
  for (int nd = 0; nd < 4; ++nd)
#pragma unroll
    for (int r = 0; r < 4; ++r) {
      size_t dst = ((size_t)b * SQ + qb + wv * 16 + lg * 4 + r) * EM + h * DHD + nd * 16 + lr;
      ctx[dst] = f2bf(cacc[nd][r] * inv[r]);
    }
  if (lr == 0) {
#pragma unroll
    for (int r = 0; r < 4; ++r) {
      int row = qb + wv * 16 + lg * 4 + r;
      mstat[headoff + row] = mrun[r];            // log2 units
      lstat[headoff + row] = 0.125f * inv[r];    // 1/(H*l): attnw uses directly
    }
  }
}

// ---------------- attn_weights: 2 k-tiles per block, XCD-swizzled 1D grid ----------------
__global__ __launch_bounds__(256) void attnw_kernel(
    const unsigned short* __restrict__ Q, const unsigned short* __restrict__ Kb,
    const float* __restrict__ mstat, const float* __restrict__ lstat,
    float* __restrict__ aw) {
  int lin = blockIdx.x;
  int xcd = lin & 7, slot = lin >> 3;          // slot 0..255
  int combo = xcd + 8 * (slot >> 5);           // (b,kt2) combo 0..63, 8 per XCD
  int qt = slot & 31;
  int kt2 = combo & 15, b = combo >> 4;
  int qb = qt * 64, kb = kt2 * 128;
  int t = threadIdx.x;
  float* tile = aw + ((size_t)b * SQ + qb) * SQ + kb;
  if (2 * kt2 > qt) {  // both 64-col tiles fully masked -> exact zeros (64x128 region)
    int row = t >> 2, cbase = (t & 3) * 32;
    f32x4 z;
#pragma unroll
    for (int j = 0; j < 4; ++j) z[j] = 0.f;
    float* p = tile + (size_t)row * SQ + cbase;
#pragma unroll
    for (int j = 0; j < 8; ++j) *(f32x4*)(p + j * 4) = z;
    return;
  }
  __shared__ unsigned short Ks[2][2][64][64];  // [dbuf][tile][kpos][dh], 32 KB
  int wv = t >> 6, ln = t & 63, lg = ln >> 4, lr = ln & 15;
  int rsub = ln >> 3;
  int csw = ((ln & 7) ^ rsub) * 8;
  size_t khstride = (size_t)SQ * DHD;
  const unsigned short* kg00 = Kb + (((size_t)b * NH) * SQ + kb + wv * 16 + rsub) * DHD + csw;
  const unsigned short* kg01 = kg00 + (size_t)8 * DHD;
  const unsigned short* kg10 = kg00 + (size_t)64 * DHD;  // second tile rows
  const unsigned short* kg11 = kg00 + (size_t)72 * DHD;
  const unsigned short* qg = Q + (((size_t)b * NH) * SQ + qb + wv * 16 + lr) * DHD + lg * 8;
  size_t mbase = (size_t)b * NH * SQ + qb + wv * 16 + lg * 4;

  // prologue: issue K head0 (both tiles) -> buf0; Q/m/l for head0 (cur) and head1 (next)
  glds16(kg00, &Ks[0][0][wv * 16][0]);
  glds16(kg01, &Ks[0][0][wv * 16 + 8][0]);
  glds16(kg10, &Ks[0][1][wv * 16][0]);
  glds16(kg11, &Ks[0][1][wv * 16 + 8][0]);

  bf16x8 aqc0 = *(const bf16x8*)qg;
  bf16x8 aqc1 = *(const bf16x8*)(qg + 32);
  bf16x8 aqn0 = *(const bf16x8*)(qg + khstride);
  bf16x8 aqn1 = *(const bf16x8*)(qg + khstride + 32);
  float mmc[4], lic[4], mmn[4], lin_[4];
#pragma unroll
  for (int r = 0; r < 4; ++r) {
    mmc[r] = mstat[mbase + r];
    lic[r] = lstat[mbase + r];
    mmn[r] = mstat[mbase + SQ + r];
    lin_[r] = lstat[mbase + SQ + r];
  }

  f32x4 facc[2][4];
#pragma unroll
  for (int j = 0; j < 2; ++j)
#pragma unroll
    for (int nt = 0; nt < 4; ++nt)
#pragma unroll
      for (int r = 0; r < 4; ++r) facc[j][nt][r] = 0.f;

  for (int h = 0; h < NH; ++h) {
    int cur = h & 1;
    __syncthreads();  // drains glds -> Ks[cur] ready
    if (h + 1 < NH) {  // issue next head's K (both tiles) into alternate buffer
      size_t ho = (size_t)(h + 1) * khstride;
      glds16(kg00 + ho, &Ks[cur ^ 1][0][wv * 16][0]);
      glds16(kg01 + ho, &Ks[cur ^ 1][0][wv * 16 + 8][0]);
      glds16(kg10 + ho, &Ks[cur ^ 1][1][wv * 16][0]);
      glds16(kg11 + ho, &Ks[cur ^ 1][1][wv * 16 + 8][0]);
    }

    // compute head h: both tiles with shared Q (no masking here)
#pragma unroll
    for (int nt = 0; nt < 4; ++nt) {
      int brw = nt * 16 + lr;
      f32x4 sf0, sf1;
#pragma unroll
      for (int r = 0; r < 4; ++r) { sf0[r] = 0.f; sf1[r] = 0.f; }
      bf16x8 bk00 = *(const bf16x8*)&Ks[cur][0][brw][sw8(brw, lg * 8)];
      bf16x8 bk01 = *(const bf16x8*)&Ks[cur][0][brw][sw8(brw, 32 + lg * 8)];
      bf16x8 bk10 = *(const bf16x8*)&Ks[cur][1][brw][sw8(brw, lg * 8)];
      bf16x8 bk11 = *(const bf16x8*)&Ks[cur][1][brw][sw8(brw, 32 + lg * 8)];
      sf0 = __builtin_amdgcn_mfma_f32_16x16x32_bf16(aqc0, bk00, sf0, 0, 0, 0);
      sf1 = __builtin_amdgcn_mfma_f32_16x16x32_bf16(aqc0, bk10, sf1, 0, 0, 0);
      sf0 = __builtin_amdgcn_mfma_f32_16x16x32_bf16(aqc1, bk01, sf0, 0, 0, 0);
      sf1 = __builtin_amdgcn_mfma_f32_16x16x32_bf16(aqc1, bk11, sf1, 0, 0, 0);
#pragma unroll
      for (int r = 0; r < 4; ++r) {
        facc[0][nt][r] += exp2f(sf0[r] - mmc[r]) * lic[r];
        facc[1][nt][r] += exp2f(sf1[r] - mmc[r]) * lic[r];
      }
    }

    // rotate Q/m/l pipeline; issue loads for head h+2
    aqc0 = aqn0; aqc1 = aqn1;
#pragma unroll
    for (int r = 0; r < 4; ++r) { mmc[r] = mmn[r]; lic[r] = lin_[r]; }
    if (h + 2 < NH) {
      aqn0 = *(const bf16x8*)(qg + (size_t)(h + 2) * khstride);
      aqn1 = *(const bf16x8*)(qg + (size_t)(h + 2) * khstride + 32);
#pragma unroll
      for (int r = 0; r < 4; ++r) {
        mmn[r] = mstat[mbase + (size_t)(h + 2) * SQ + r];
        lin_[r] = lstat[mbase + (size_t)(h + 2) * SQ + r];
      }
    }
  }

  // write; masking applied once per tile: full-mask / diagonal / none
#pragma unroll
  for (int j = 0; j < 2; ++j) {
    int ktj = 2 * kt2 + j;
    bool fullmask = (ktj > qt);
    bool dg = (ktj == qt);
#pragma unroll
    for (int nt = 0; nt < 4; ++nt) {
      int kc = kb + j * 64 + nt * 16 + lr;
#pragma unroll
      for (int r = 0; r < 4; ++r) {
        int qr = qb + wv * 16 + lg * 4 + r;
        float v = (fullmask || (dg && kc > qr)) ? 0.f : facc[j][nt][r];
        tile[(size_t)(wv * 16 + lg * 4 + r) * SQ + j * 64 + nt * 16 + lr] = v;
      }
    }
  }
}

extern "C" void kernel_launch(void* const* d_in, const int* in_sizes, int n_in,
                              void* d_out, int out_size, void* d_ws, size_t ws_size,
                              hipStream_t stream) {
  (void)in_sizes; (void)n_in; (void)out_size; (void)ws_size;
  const float* x = (const float*)d_in[0];
  const float* ln1g = (const float*)d_in[1];
  const float* ln1b = (const float*)d_in[2];
  const float* wqkv = (const float*)d_in[3];
  const float* bqkv = (const float*)d_in[4];
  const float* wout = (const float*)d_in[5];
  const float* bout = (const float*)d_in[6];
  const float* ln2g = (const float*)d_in[7];
  const float* ln2b = (const float*)d_in[8];
  const float* wfc1 = (const float*)d_in[9];
  const float* bfc1 = (const float*)d_in[10];
  const float* wfc2 = (const float*)d_in[11];
  const float* bfc2 = (const float*)d_in[12];

  char* ws = (char*)d_ws;
  unsigned short* zctx = (unsigned short*)(ws);               // z (bf16), later reused as ctx
  unsigned short* qb_ = (unsigned short*)(ws + 8388608);      // later reused as LN2 out
  unsigned short* kb_ = (unsigned short*)(ws + 16777216);     // later reused as fc1 out
  unsigned short* vb_ = (unsigned short*)(ws + 25165824);     // V^T [b,h,d,s]
  float* z2 = (float*)(ws + 33554432);                        // fp32 residual stream
  float* mstat = (float*)(ws + 50331648);
  float* lstat = (float*)(ws + 50593792);
  unsigned short* wqkv_h = (unsigned short*)(ws + 50855936);
  unsigned short* wout_h = (unsigned short*)(ws + 52428800);
  unsigned short* wfc1_h = (unsigned short*)(ws + 52953088);
  unsigned short* wfc2_h = (unsigned short*)(ws + 53477376);
  unsigned short* y1 = qb_;
  unsigned short* h1 = kb_;

  float* outy = (float*)d_out;
  float* outw = outy + (size_t)NB * SQ * EM;

  f2bf4_kernel<<<768, 256, 0, stream>>>(wqkv, wout, wfc1, wfc2,
                                        wqkv_h, wout_h, wfc1_h, wfc2_h);

  ln_kernel<<<2048, 256, 0, stream>>>(x, ln1g, ln1b, zctx);
  gemm128qkv<<<768, 256, 0, stream>>>(zctx, wqkv_h, bqkv, qb_, kb_, vb_, 512);
  flash_kernel<<<1024, 256, 0, stream>>>(qb_, kb_, vb_, zctx, mstat, lstat);
  attnw_kernel<<<2048, 256, 0, stream>>>(qb_, kb_, mstat, lstat, outw);
  gemm64<false, true, true, false><<<dim3(128, 8), 256, 0, stream>>>(
      zctx, wout_h, bout, x, z2, nullptr, nullptr, nullptr, nullptr, 8192, 512, 512);
  ln_kernel<<<2048, 256, 0, stream>>>(z2, ln2g, ln2b, y1);
  gemm64<true, false, false, false><<<dim3(128, 8), 256, 0, stream>>>(
      y1, wfc1_h, bfc1, nullptr, nullptr, h1, nullptr, nullptr, nullptr, 8192, 512, 512);
  gemm64<false, true, true, false><<<dim3(128, 8), 256, 0, stream>>>(
      h1, wfc2_h, bfc2, z2, outy, nullptr, nullptr, nullptr, nullptr, 8192, 512, 512);
}